// Round 8
// baseline (76.707 us; speedup 1.0000x reference)
//
#include <hip/hip_runtime.h>

#ifndef FLT_MAX
#define FLT_MAX 3.402823466e+38f
#endif

typedef float v2f __attribute__((ext_vector_type(2)));
typedef float v4f __attribute__((ext_vector_type(4)));

__device__ __forceinline__ float sel3(int i, float a, float b, float c) {
    return i == 0 ? a : (i == 1 ? b : c);
}

// Deterministic d2: sub,sub,sub,mul,fma,fma — element-wise identical to the
// packed phase-1 pipeline, so phase-2 recomputed values are bit-identical.
__device__ __forceinline__ float d2f(float ax, float ay, float az,
                                     float bx, float by, float bz) {
    const float dx = __fsub_rn(ax, bx);
    const float dy = __fsub_rn(ay, by);
    const float dz = __fsub_rn(az, bz);
    return __builtin_fmaf(dx, dx, __builtin_fmaf(dy, dy, __fmul_rn(dz, dz)));
}

__device__ __forceinline__ v2f d2p(v2f ax, v2f ay, v2f az, v2f bx, v2f by, v2f bz) {
    const v2f dx = ax - bx, dy = ay - by, dz = az - bz;
    return __builtin_elementwise_fma(dx, dx,
           __builtin_elementwise_fma(dy, dy, dz * dz));
}

// FOUR edges per 64-lane wave (16-lane group n = lanes 16n..16n+15 owns edge n).
// Lane 16n+t owns rows {t,t+16,t+32,t+48} of x1 and cols {t,t+16,t+32,t+48} of
// x2 (edge n). x2 staged in per-edge LDS slices PADDED to 784B so slice n
// starts at bank 4n: each scan ds_read_b128 carries 4 distinct addresses on
// DISJOINT bank quads -> one ~12cyc LDS transaction broadcasts a 4-column
// group for all 4 edges (12 b128-equiv/edge vs 48 in R5, 2x-conflicted 24 in
// R7). Value-only packed scan + bit-exact recompute (numpy argmin semantics).
#define SLICE 196   // 3*64 floats + 4 pad = 784B; 784/4 % 32 = 4 banks shift

__global__ __launch_bounds__(256, 8) void clustgeo_edge_kernel(
    const float* __restrict__ data,    // (N,4) f32; coords = cols 1..3
    const int*   __restrict__ clusts,  // (C,64) int (harness-converted from i64)
    const int*   __restrict__ eidx,    // (2,E)  int
    float*       __restrict__ out,     // (E,19) f32
    int E)
{
    const int wave = threadIdx.x >> 6;
    const int lane = threadIdx.x & 63;
    const int t    = lane & 15;          // position within 16-lane group
    const int gsh  = lane & 48;          // 16*n (ballot shift amount)
    const int e    = blockIdx.x * 16 + wave * 4 + (lane >> 4);
    const int ec   = e < E ? e : (E - 1);

    __shared__ __align__(16) float sx[4][4][SLICE];   // [wave][edge-group][slice]

    const int ca = eidx[ec];
    const int cb = eidx[E + ec];
    const int cb64 = cb * 64 + t;
    const int ca64 = ca * 64 + t;

    // Gather rows (x1) and cols (x2): 4 each, strided 16.
    const int p10 = clusts[ca64], p11 = clusts[ca64+16], p12 = clusts[ca64+32], p13 = clusts[ca64+48];
    const int p20 = clusts[cb64], p21 = clusts[cb64+16], p22 = clusts[cb64+32], p23 = clusts[cb64+48];
    const float4 q10 = *reinterpret_cast<const float4*>(data + (size_t)p10 * 4);
    const float4 q11 = *reinterpret_cast<const float4*>(data + (size_t)p11 * 4);
    const float4 q12 = *reinterpret_cast<const float4*>(data + (size_t)p12 * 4);
    const float4 q13 = *reinterpret_cast<const float4*>(data + (size_t)p13 * 4);
    const float4 q20 = *reinterpret_cast<const float4*>(data + (size_t)p20 * 4);
    const float4 q21 = *reinterpret_cast<const float4*>(data + (size_t)p21 * 4);
    const float4 q22 = *reinterpret_cast<const float4*>(data + (size_t)p22 * 4);
    const float4 q23 = *reinterpret_cast<const float4*>(data + (size_t)p23 * 4);
    const float r0x=q10.y, r0y=q10.z, r0z=q10.w;   // row t
    const float r1x=q11.y, r1y=q11.z, r1z=q11.w;   // row t+16
    const float r2x=q12.y, r2y=q12.z, r2z=q12.w;   // row t+32
    const float r3x=q13.y, r3y=q13.z, r3z=q13.w;   // row t+48

    float* slice = &sx[wave][lane >> 4][0];        // this group's slice
    // SoA within slice: comp c at c*64 floats, col j at +j.
    slice[t     ] = q20.y; slice[t+16     ] = q21.y; slice[t+32     ] = q22.y; slice[t+48     ] = q23.y;
    slice[t+64  ] = q20.z; slice[t+16+64  ] = q21.z; slice[t+32+64  ] = q22.z; slice[t+48+64  ] = q23.z;
    slice[t+128 ] = q20.w; slice[t+16+128 ] = q21.w; slice[t+32+128 ] = q22.w; slice[t+48+128 ] = q23.w;
    // No barrier: each group reads only its own slice; same-wave LDS RAW is
    // ordered by compiler-inserted lgkmcnt waits (validated R3-R7).

    const v4f* SL = reinterpret_cast<const v4f*>(slice);   // [c*16 + g]

    // Phase 1: packed value-only min. One v2f accumulator per owned row.
    v2f a0 = {FLT_MAX, FLT_MAX}, a1 = {FLT_MAX, FLT_MAX};
    v2f a2 = {FLT_MAX, FLT_MAX}, a3 = {FLT_MAX, FLT_MAX};
    #pragma unroll 4
    for (int g = 0; g < 16; ++g) {
        const v4f X = SL[g];
        const v4f Y = SL[16 + g];
        const v4f Z = SL[32 + g];
        const v2f xlo = X.xy, xhi = X.zw, ylo = Y.xy, yhi = Y.zw, zlo = Z.xy, zhi = Z.zw;
        a0 = __builtin_elementwise_min(a0, d2p((v2f){r0x,r0x},(v2f){r0y,r0y},(v2f){r0z,r0z}, xlo, ylo, zlo));
        a0 = __builtin_elementwise_min(a0, d2p((v2f){r0x,r0x},(v2f){r0y,r0y},(v2f){r0z,r0z}, xhi, yhi, zhi));
        a1 = __builtin_elementwise_min(a1, d2p((v2f){r1x,r1x},(v2f){r1y,r1y},(v2f){r1z,r1z}, xlo, ylo, zlo));
        a1 = __builtin_elementwise_min(a1, d2p((v2f){r1x,r1x},(v2f){r1y,r1y},(v2f){r1z,r1z}, xhi, yhi, zhi));
        a2 = __builtin_elementwise_min(a2, d2p((v2f){r2x,r2x},(v2f){r2y,r2y},(v2f){r2z,r2z}, xlo, ylo, zlo));
        a2 = __builtin_elementwise_min(a2, d2p((v2f){r2x,r2x},(v2f){r2y,r2y},(v2f){r2z,r2z}, xhi, yhi, zhi));
        a3 = __builtin_elementwise_min(a3, d2p((v2f){r3x,r3x},(v2f){r3y,r3y},(v2f){r3z,r3z}, xlo, ylo, zlo));
        a3 = __builtin_elementwise_min(a3, d2p((v2f){r3x,r3x},(v2f){r3y,r3y},(v2f){r3z,r3z}, xhi, yhi, zhi));
    }
    const float m0 = fminf(a0.x, a0.y);
    const float m1 = fminf(a1.x, a1.y);
    const float m2 = fminf(a2.x, a2.y);
    const float m3 = fminf(a3.x, a3.y);

    // Group (16-lane) min: xor-butterfly, offsets stay inside the group.
    float bmn = fminf(fminf(m0, m1), fminf(m2, m3));
    #pragma unroll
    for (int off = 8; off; off >>= 1) bmn = fminf(bmn, __shfl_xor(bmn, off, 64));

    // First row attaining min: slots r in ascending order (row = 16r + t),
    // within a slot lowest t = lowest flattened row. numpy row-major first.
    const unsigned g0 = (unsigned)(__ballot(m0 == bmn) >> gsh) & 0xFFFFu;
    const unsigned g1 = (unsigned)(__ballot(m1 == bmn) >> gsh) & 0xFFFFu;
    const unsigned g2 = (unsigned)(__ballot(m2 == bmn) >> gsh) & 0xFFFFu;
    const unsigned g3 = (unsigned)(__ballot(m3 == bmn) >> gsh) & 0xFFFFu;
    const int i1 = g0 ? __builtin_ctz(g0)
                 : g1 ? 16 + __builtin_ctz(g1)
                 : g2 ? 32 + __builtin_ctz(g2)
                 :      48 + __builtin_ctz(g3);

    // v1 = x1[i1]: slot-select then broadcast from owning lane (per-group shfl).
    const int rw = i1 >> 4;
    const int wl = gsh + (i1 & 15);
    const float c1x = rw == 0 ? r0x : rw == 1 ? r1x : rw == 2 ? r2x : r3x;
    const float c1y = rw == 0 ? r0y : rw == 1 ? r1y : rw == 2 ? r2y : r3y;
    const float c1z = rw == 0 ? r0z : rw == 1 ? r1z : rw == 2 ? r2z : r3z;
    const float v1x = __shfl(c1x, wl, 64);
    const float v1y = __shfl(c1y, wl, 64);
    const float v1z = __shfl(c1z, wl, 64);

    // Phase 2: recompute row i1 over this lane's 4 cols (re-read from LDS;
    // d2f bit-identical to phase 1 -> first-match col is exact).
    const float d0 = d2f(v1x, v1y, v1z, slice[t],     slice[t+64],     slice[t+128]);
    const float d1 = d2f(v1x, v1y, v1z, slice[t+16],  slice[t+16+64],  slice[t+16+128]);
    const float d2_ = d2f(v1x, v1y, v1z, slice[t+32], slice[t+32+64],  slice[t+32+128]);
    const float d3 = d2f(v1x, v1y, v1z, slice[t+48],  slice[t+48+64],  slice[t+48+128]);
    const unsigned h0 = (unsigned)(__ballot(d0 == bmn) >> gsh) & 0xFFFFu;
    const unsigned h1 = (unsigned)(__ballot(d1 == bmn) >> gsh) & 0xFFFFu;
    const unsigned h2 = (unsigned)(__ballot(d2_ == bmn) >> gsh) & 0xFFFFu;
    const unsigned h3 = (unsigned)(__ballot(d3 == bmn) >> gsh) & 0xFFFFu;
    const int i2 = h0 ? __builtin_ctz(h0)
                 : h1 ? 16 + __builtin_ctz(h1)
                 : h2 ? 32 + __builtin_ctz(h2)
                 :      48 + __builtin_ctz(h3);

    const float v2x = slice[i2];
    const float v2y = slice[i2 + 64];
    const float v2z = slice[i2 + 128];

    float dx = v1x - v2x, dy = v1y - v2y, dz = v1z - v2z;
    const float lend = sqrtf(dx * dx + dy * dy + dz * dz);
    if (lend > 0.f) { dx /= lend; dy /= lend; dz /= lend; }

    // 19 outputs from 16 lanes: lane t stores element t, and t+16 if t<3.
    if (e < E) {
        float* orow = out + (size_t)e * 19;
        float o;
        if (t < 3)       o = sel3(t,     v1x, v1y, v1z);
        else if (t < 6)  o = sel3(t - 3, v2x, v2y, v2z);
        else if (t < 9)  o = sel3(t - 6, dx, dy, dz);
        else if (t == 9) o = lend;
        else {
            const int k = t - 10;
            o = sel3(k / 3, dx, dy, dz) * sel3(k % 3, dx, dy, dz);
        }
        orow[t] = o;
        if (t < 3) {
            const int k = t + 6;   // elements 16,17,18 = B[6..8]
            orow[16 + t] = sel3(k / 3, dx, dy, dz) * sel3(k % 3, dx, dy, dz);
        }
    }
}

extern "C" void kernel_launch(void* const* d_in, const int* in_sizes, int n_in,
                              void* d_out, int out_size, void* d_ws, size_t ws_size,
                              hipStream_t stream) {
    const float* data   = (const float*)d_in[0];
    const int*   clusts = (const int*)d_in[1];
    const int*   eidx   = (const int*)d_in[2];
    float*       out    = (float*)d_out;
    const int E = in_sizes[2] / 2;            // edge_index is (2, E)
    const int blocks = (E + 15) / 16;         // 16 edges per block (4 waves x 4)
    clustgeo_edge_kernel<<<blocks, 256, 0, stream>>>(data, clusts, eidx, out, E);
}

// Round 9
// 31.870 us; speedup vs baseline: 2.4069x; 2.4069x over previous
//
#include <hip/hip_runtime.h>

#ifndef FLT_MAX
#define FLT_MAX 3.402823466e+38f
#endif

typedef float v2f __attribute__((ext_vector_type(2)));
typedef float v4f __attribute__((ext_vector_type(4)));

__device__ __forceinline__ float sel3(int i, float a, float b, float c) {
    return i == 0 ? a : (i == 1 ? b : c);
}

__device__ __forceinline__ float sel4(int i, float a, float b, float c, float d) {
    return i == 0 ? a : (i == 1 ? b : (i == 2 ? c : d));
}

// Deterministic d2 (scalar), element-wise identical to packed pipeline below.
__device__ __forceinline__ float d2f(float ax, float ay, float az,
                                     float bx, float by, float bz) {
    const float dx = __fsub_rn(ax, bx);
    const float dy = __fsub_rn(ay, by);
    const float dz = __fsub_rn(az, bz);
    return __builtin_fmaf(dx, dx, __builtin_fmaf(dy, dy, __fmul_rn(dz, dz)));
}

__device__ __forceinline__ v2f d2p(v2f ax, v2f ay, v2f az, v2f bx, v2f by, v2f bz) {
    const v2f dx = ax - bx, dy = ay - by, dz = az - bz;
    return __builtin_elementwise_fma(dx, dx,
           __builtin_elementwise_fma(dy, dy, dz * dz));
}

// FOUR edges per 64-lane wave; 16-lane group n owns edge n. Lane 16n+t owns
// rows 4t..4t+3 of x1 and cols 4t..4t+3 of x2 (consecutive -> int4 clusts
// loads, ds_write_b128 staging). Per-edge LDS slice padded to 196 floats
// (49 b128 quads) so the scan's one ds_read_b128 per (comp,group) carries 4
// addresses on DISJOINT bank quads {g,g+17,g+2,g+19 mod 32} -> ~12cyc each,
// 12 reads/edge. Value-only packed scan; bit-exact register recompute.
#define SLICE 196

__global__ __launch_bounds__(256, 4) void clustgeo_edge_kernel(
    const float* __restrict__ data,    // (N,4) f32; coords = cols 1..3
    const int*   __restrict__ clusts,  // (C,64) int (harness-converted from i64)
    const int*   __restrict__ eidx,    // (2,E)  int
    float*       __restrict__ out,     // (E,19) f32
    int E)
{
    const int wave = threadIdx.x >> 6;
    const int lane = threadIdx.x & 63;
    const int t    = lane & 15;          // position within 16-lane group
    const int gsh  = lane & 48;          // 16*n (ballot shift amount)
    const int e    = blockIdx.x * 16 + wave * 4 + (lane >> 4);
    const int ec   = e < E ? e : (E - 1);

    __shared__ __align__(16) float sx[4][4][SLICE];   // [wave][group][slice]

    const int ca = eidx[ec];
    const int cb = eidx[E + ec];

    // Coalesced index loads: 4 consecutive point ids per lane.
    const int4 P1 = *reinterpret_cast<const int4*>(clusts + ca * 64 + 4 * t);
    const int4 P2 = *reinterpret_cast<const int4*>(clusts + cb * 64 + 4 * t);
    const float4 q10 = *reinterpret_cast<const float4*>(data + (size_t)P1.x * 4);
    const float4 q11 = *reinterpret_cast<const float4*>(data + (size_t)P1.y * 4);
    const float4 q12 = *reinterpret_cast<const float4*>(data + (size_t)P1.z * 4);
    const float4 q13 = *reinterpret_cast<const float4*>(data + (size_t)P1.w * 4);
    const float4 q20 = *reinterpret_cast<const float4*>(data + (size_t)P2.x * 4);
    const float4 q21 = *reinterpret_cast<const float4*>(data + (size_t)P2.y * 4);
    const float4 q22 = *reinterpret_cast<const float4*>(data + (size_t)P2.z * 4);
    const float4 q23 = *reinterpret_cast<const float4*>(data + (size_t)P2.w * 4);
    // x1 rows 4t+r in regs.
    const float r0x=q10.y, r0y=q10.z, r0z=q10.w;
    const float r1x=q11.y, r1y=q11.z, r1z=q11.w;
    const float r2x=q12.y, r2y=q12.z, r2z=q12.w;
    const float r3x=q13.y, r3y=q13.z, r3z=q13.w;
    // x2 cols 4t+r in regs (phase-2 recompute source).
    const float c0x=q20.y, c0y=q20.z, c0z=q20.w;
    const float c1x=q21.y, c1y=q21.z, c1z=q21.w;
    const float c2x=q22.y, c2y=q22.z, c2z=q22.w;
    const float c3x=q23.y, c3y=q23.z, c3z=q23.w;

    float* slice = &sx[wave][lane >> 4][0];   // SoA: comp c at c*64 + col
    *reinterpret_cast<v4f*>(slice + 4 * t)       = (v4f){c0x, c1x, c2x, c3x};
    *reinterpret_cast<v4f*>(slice + 64 + 4 * t)  = (v4f){c0y, c1y, c2y, c3y};
    *reinterpret_cast<v4f*>(slice + 128 + 4 * t) = (v4f){c0z, c1z, c2z, c3z};
    // No barrier: each group reads only its own slice; same-wave LDS RAW is
    // ordered by compiler-inserted lgkmcnt waits (validated R3-R8).

    const v4f* SL = reinterpret_cast<const v4f*>(slice);   // [c*16 + g]

    // Phase 1: packed value-only min, one v2f accumulator per owned row slot.
    v2f a0 = {FLT_MAX, FLT_MAX}, a1 = {FLT_MAX, FLT_MAX};
    v2f a2 = {FLT_MAX, FLT_MAX}, a3 = {FLT_MAX, FLT_MAX};
    #pragma unroll 2
    for (int g = 0; g < 16; ++g) {
        const v4f X = SL[g];
        const v4f Y = SL[16 + g];
        const v4f Z = SL[32 + g];
        const v2f xlo = X.xy, xhi = X.zw, ylo = Y.xy, yhi = Y.zw, zlo = Z.xy, zhi = Z.zw;
        a0 = __builtin_elementwise_min(a0, d2p((v2f){r0x,r0x},(v2f){r0y,r0y},(v2f){r0z,r0z}, xlo, ylo, zlo));
        a0 = __builtin_elementwise_min(a0, d2p((v2f){r0x,r0x},(v2f){r0y,r0y},(v2f){r0z,r0z}, xhi, yhi, zhi));
        a1 = __builtin_elementwise_min(a1, d2p((v2f){r1x,r1x},(v2f){r1y,r1y},(v2f){r1z,r1z}, xlo, ylo, zlo));
        a1 = __builtin_elementwise_min(a1, d2p((v2f){r1x,r1x},(v2f){r1y,r1y},(v2f){r1z,r1z}, xhi, yhi, zhi));
        a2 = __builtin_elementwise_min(a2, d2p((v2f){r2x,r2x},(v2f){r2y,r2y},(v2f){r2z,r2z}, xlo, ylo, zlo));
        a2 = __builtin_elementwise_min(a2, d2p((v2f){r2x,r2x},(v2f){r2y,r2y},(v2f){r2z,r2z}, xhi, yhi, zhi));
        a3 = __builtin_elementwise_min(a3, d2p((v2f){r3x,r3x},(v2f){r3y,r3y},(v2f){r3z,r3z}, xlo, ylo, zlo));
        a3 = __builtin_elementwise_min(a3, d2p((v2f){r3x,r3x},(v2f){r3y,r3y},(v2f){r3z,r3z}, xhi, yhi, zhi));
    }
    const float m0 = fminf(a0.x, a0.y);
    const float m1 = fminf(a1.x, a1.y);
    const float m2 = fminf(a2.x, a2.y);
    const float m3 = fminf(a3.x, a3.y);

    // Group (16-lane) min.
    float bmn = fminf(fminf(m0, m1), fminf(m2, m3));
    #pragma unroll
    for (int off = 8; off; off >>= 1) bmn = fminf(bmn, __shfl_xor(bmn, off, 64));

    // First row attaining min. Row = 4t + r: ascending rows = lexicographic
    // (t, r), so lowest t with any winner, then lowest winning slot there.
    const unsigned g0 = (unsigned)(__ballot(m0 == bmn) >> gsh) & 0xFFFFu;
    const unsigned g1 = (unsigned)(__ballot(m1 == bmn) >> gsh) & 0xFFFFu;
    const unsigned g2 = (unsigned)(__ballot(m2 == bmn) >> gsh) & 0xFFFFu;
    const unsigned g3 = (unsigned)(__ballot(m3 == bmn) >> gsh) & 0xFFFFu;
    const int t1 = __builtin_ctz(g0 | g1 | g2 | g3);
    const int s1 = (g0 >> t1) & 1 ? 0 : (g1 >> t1) & 1 ? 1 : (g2 >> t1) & 1 ? 2 : 3;

    // v1 broadcast: every lane selects its slot-s1 row, shfl from lane t1.
    const float v1x = __shfl(sel4(s1, r0x, r1x, r2x, r3x), gsh + t1, 64);
    const float v1y = __shfl(sel4(s1, r0y, r1y, r2y, r3y), gsh + t1, 64);
    const float v1z = __shfl(sel4(s1, r0z, r1z, r2z, r3z), gsh + t1, 64);

    // Phase 2: recompute row i1 over this lane's 4 register-held cols;
    // d2f bit-identical to d2p -> first-match col is exact.
    const float d0 = d2f(v1x, v1y, v1z, c0x, c0y, c0z);
    const float d1 = d2f(v1x, v1y, v1z, c1x, c1y, c1z);
    const float d2_ = d2f(v1x, v1y, v1z, c2x, c2y, c2z);
    const float d3 = d2f(v1x, v1y, v1z, c3x, c3y, c3z);
    const unsigned h0 = (unsigned)(__ballot(d0 == bmn) >> gsh) & 0xFFFFu;
    const unsigned h1 = (unsigned)(__ballot(d1 == bmn) >> gsh) & 0xFFFFu;
    const unsigned h2 = (unsigned)(__ballot(d2_ == bmn) >> gsh) & 0xFFFFu;
    const unsigned h3 = (unsigned)(__ballot(d3 == bmn) >> gsh) & 0xFFFFu;
    const int t2 = __builtin_ctz(h0 | h1 | h2 | h3);
    const int s2 = (h0 >> t2) & 1 ? 0 : (h1 >> t2) & 1 ? 1 : (h2 >> t2) & 1 ? 2 : 3;

    const float v2x = __shfl(sel4(s2, c0x, c1x, c2x, c3x), gsh + t2, 64);
    const float v2y = __shfl(sel4(s2, c0y, c1y, c2y, c3y), gsh + t2, 64);
    const float v2z = __shfl(sel4(s2, c0z, c1z, c2z, c3z), gsh + t2, 64);

    float dx = v1x - v2x, dy = v1y - v2y, dz = v1z - v2z;
    const float lend = sqrtf(dx * dx + dy * dy + dz * dz);
    if (lend > 0.f) { dx /= lend; dy /= lend; dz /= lend; }

    // 19 outputs from 16 lanes: lane t stores element t, and 16+t if t<3.
    if (e < E) {
        float* orow = out + (size_t)e * 19;
        float o;
        if (t < 3)       o = sel3(t,     v1x, v1y, v1z);
        else if (t < 6)  o = sel3(t - 3, v2x, v2y, v2z);
        else if (t < 9)  o = sel3(t - 6, dx, dy, dz);
        else if (t == 9) o = lend;
        else {
            const int k = t - 10;
            o = sel3(k / 3, dx, dy, dz) * sel3(k % 3, dx, dy, dz);
        }
        orow[t] = o;
        if (t < 3) {
            const int k = t + 6;   // elements 16,17,18 = B[6..8]
            orow[16 + t] = sel3(k / 3, dx, dy, dz) * sel3(k % 3, dx, dy, dz);
        }
    }
}

extern "C" void kernel_launch(void* const* d_in, const int* in_sizes, int n_in,
                              void* d_out, int out_size, void* d_ws, size_t ws_size,
                              hipStream_t stream) {
    const float* data   = (const float*)d_in[0];
    const int*   clusts = (const int*)d_in[1];
    const int*   eidx   = (const int*)d_in[2];
    float*       out    = (float*)d_out;
    const int E = in_sizes[2] / 2;            // edge_index is (2, E)
    const int blocks = (E + 15) / 16;         // 16 edges per block (4 waves x 4)
    clustgeo_edge_kernel<<<blocks, 256, 0, stream>>>(data, clusts, eidx, out, E);
}